// Round 16
// baseline (47.233 us; speedup 1.0000x reference)
//
#include <hip/hip_runtime.h>
#include <hip/hip_bf16.h>

typedef __attribute__((ext_vector_type(8))) short short8;
typedef __attribute__((ext_vector_type(4))) float f32x4;

#define NTOK 4096
#define DIN  1024
#define DOUT 1024
#define KTOT 1152   // 1024 (W) + 128 (LoRA)
#define XLD  1152
#define TLDS 200    // Tsm leading dim (f32)

__device__ __forceinline__ unsigned short f2bf(float f) {
    __hip_bfloat16 h = __float2bfloat16(f);
    return __builtin_bit_cast(unsigned short, h);
}

__device__ __forceinline__ void gload16(const void* g, void* l) {
    __builtin_amdgcn_global_load_lds((const __attribute__((address_space(1))) void*)g,
                                     (__attribute__((address_space(3))) void*)l, 16, 0, 0);
}

__device__ __forceinline__ uint4 pack2(float4 v0, float4 v1) {
    union { unsigned short u[8]; uint4 q; } pk;
    pk.u[0] = f2bf(v0.x); pk.u[1] = f2bf(v0.y); pk.u[2] = f2bf(v0.z); pk.u[3] = f2bf(v0.w);
    pk.u[4] = f2bf(v1.x); pk.u[5] = f2bf(v1.y); pk.u[6] = f2bf(v1.z); pk.u[7] = f2bf(v1.w);
    return pk.q;
}

__device__ __forceinline__ uint4 pack8(const float* s) {
    return pack2(*(const float4*)s, *(const float4*)(s + 4));
}

// ==== Launch 1: independent block ranges, no intra-launch dependencies ======
//   b <  256 : gemm1 (reads x, lora_U, gate_w f32) -> coef into Xcat[:,1024:]
//   b < 2304 : cvtx  (x f32 -> Xcat[:, :1024] bf16)
//   b < 2880 : cvtw  (Wcat = [W | V2] bf16)
__global__ __launch_bounds__(256) void k_prep_g1(const float* __restrict__ x,
                                                 const float* __restrict__ lora_U,
                                                 const float* __restrict__ gate_w,
                                                 const float* __restrict__ w,
                                                 const float* __restrict__ lora_V,
                                                 __hip_bfloat16* __restrict__ Xcat,
                                                 __hip_bfloat16* __restrict__ Wcat) {
    __shared__ char smem[49152];                   // gemm1: B dbuf 2x24KB; Tsm reuse
    const int bid = blockIdx.x;
    const int t = threadIdx.x;

    if (bid >= 256) {
        if (bid < 2304) {                          // ---- cvtx ----
            int idx = (bid - 256) * 256 + t;       // 4096 rows x 128 groups
            int n = idx >> 7, g = idx & 127;
            *(uint4*)(Xcat + (size_t)n * XLD + g * 8) = pack8(x + (size_t)n * DIN + g * 8);
        } else {                                   // ---- cvtw ----
            int idx = (bid - 2304) * 256 + t;      // 1024 rows x 144 groups
            int o = idx / 144, g = idx - o * 144;
            const float* s;
            if (g < 128) s = w + (size_t)o * DIN + g * 8;
            else {
                int i0 = (g - 128) * 8;
                int e = i0 >> 4, r = i0 & 15;
                s = lora_V + (size_t)e * (DOUT * 16) + (size_t)o * 16 + r;
            }
            *(uint4*)(Wcat + (size_t)o * KTOT + g * 8) = pack8(s);
        }
        return;
    }

    // ---- gemm1: T = x @ [lora_U;gate_w]^T (K=1024), softmax, coef ----------
    // BM=16, BN=192, BK=64, 4 waves. Reg-staged B (f32->bf16->swizzled ds_write),
    // double-buffered; A f32 direct-to-reg. All loads compiler-tracked.
    float (*Tsm)[TLDS] = (float(*)[TLDS])smem;
    const int lane = t & 63, wid = t >> 6;
    const int row0 = bid * 16;
    const int l7 = lane & 7, l15 = lane & 15, l16 = lane >> 4;

    f32x4 acc[3];
#pragma unroll
    for (int n = 0; n < 3; ++n) acc[n] = (f32x4){0.f, 0.f, 0.f, 0.f};

    int boff[3];
#pragma unroll
    for (int n = 0; n < 3; ++n) boff[n] = (wid * 48 + n * 16 + l15) * 128;
    int sw[2];
#pragma unroll
    for (int ks = 0; ks < 2; ++ks) sw[ks] = (((ks * 4 + l16) ^ l7) << 4);

    // B staging task map: c=0..5 -> row rr=c*32+(t>>3), colgrp p=t&7.
    const int trow = t >> 3, p = t & 7;
    int bdst[6];                                   // LDS byte offset (swizzled)
    const float* bsrc[6];                          // f32 source row base (or null)
#pragma unroll
    for (int c = 0; c < 6; ++c) {
        int rr = c * 32 + trow;
        bdst[c] = (rr >> 3) * 1024 + (((rr & 7) * 8 + p) * 16);
        int scol8 = ((p ^ (rr & 7)) << 3);         // swizzled source col
        if (rr < 128)      bsrc[c] = lora_U + (size_t)rr * DIN + scol8;
        else if (rr < 136) bsrc[c] = gate_w + (size_t)(rr - 128) * DIN + scol8;
        else               bsrc[c] = nullptr;
    }
    const float* arow = x + (size_t)(row0 + l15) * DIN + l16 * 8;

    // prologue: stage B(0) -> buf0, A(0) -> areg
    short8 areg;
    {
#pragma unroll
        for (int c = 0; c < 6; ++c) {
            uint4 q = bsrc[c] ? pack8(bsrc[c]) : make_uint4(0u, 0u, 0u, 0u);
            *(uint4*)(smem + bdst[c]) = q;
        }
        union { unsigned short u[8]; short8 s8; } pa;
        float4 a0 = *(const float4*)arow, a1 = *(const float4*)(arow + 4);
        pa.u[0]=f2bf(a0.x); pa.u[1]=f2bf(a0.y); pa.u[2]=f2bf(a0.z); pa.u[3]=f2bf(a0.w);
        pa.u[4]=f2bf(a1.x); pa.u[5]=f2bf(a1.y); pa.u[6]=f2bf(a1.z); pa.u[7]=f2bf(a1.w);
        areg = pa.s8;
    }
    __syncthreads();

    for (int kt = 0; kt < 16; ++kt) {
        const int cur = kt & 1;
        float4 bpre[6][2]; float4 apre0, apre1;
        const bool hasNext = kt < 15;
        if (hasNext) {                             // issue next-tile loads early
            const int k1 = (kt + 1) << 6;
#pragma unroll
            for (int c = 0; c < 6; ++c)
                if (bsrc[c]) {
                    bpre[c][0] = *(const float4*)(bsrc[c] + k1);
                    bpre[c][1] = *(const float4*)(bsrc[c] + k1 + 4);
                }
            apre0 = *(const float4*)(arow + k1);
            apre1 = *(const float4*)(arow + k1 + 4);
        }
        // MFMA on current buffer (hides the loads above)
        const char* Bb = smem + cur * 24576;
#pragma unroll
        for (int ks = 0; ks < 2; ++ks) {
            short8 af = areg;
            if (ks == 1) {                         // shift areg: cols l16*8+? no-
                // areg holds 8 bf16 = K-slice l16*8..+7 of 32-wide ks chunk:
                // done via two loads below instead
            }
            (void)af;
        }
        // NOTE: A fragment for ks=0 uses cols l16*8 (lanes 0-63 cover 0..31 via l16*8?
        // l16 in 0..3 -> cols 0..31 => ks=0 chunk; ks=1 chunk = cols 32..63.
        {
            short8 af0 = areg;                     // cols kt*64 + l16*8 (ks=0)
            union { unsigned short u[8]; short8 s8; } pa1;
            float4 a2 = *(const float4*)(arow + (kt << 6) + 32);
            float4 a3 = *(const float4*)(arow + (kt << 6) + 36);
            pa1.u[0]=f2bf(a2.x); pa1.u[1]=f2bf(a2.y); pa1.u[2]=f2bf(a2.z); pa1.u[3]=f2bf(a2.w);
            pa1.u[4]=f2bf(a3.x); pa1.u[5]=f2bf(a3.y); pa1.u[6]=f2bf(a3.z); pa1.u[7]=f2bf(a3.w);
            short8 af1 = pa1.s8;                   // cols kt*64+32+l16*8 (ks=1)
            // fix: af1 must be at +32 + l16*8 -> recompute with lane offset
            float4 b2 = *(const float4*)(arow + (kt << 6) + 32 + 0);
            (void)b2;
#pragma unroll
            for (int n = 0; n < 3; ++n) {
                short8 bf0 = *(const short8*)(Bb + boff[n] + sw[0]);
                acc[n] = __builtin_amdgcn_mfma_f32_16x16x32_bf16(af0, bf0, acc[n], 0, 0, 0);
            }
#pragma unroll
            for (int n = 0; n < 3; ++n) {
                short8 bf1 = *(const short8*)(Bb + boff[n] + sw[1]);
                acc[n] = __builtin_amdgcn_mfma_f32_16x16x32_bf16(af1, bf1, acc[n], 0, 0, 0);
            }
        }
        if (hasNext) {                             // convert + ds_write late
#pragma unroll
            for (int c = 0; c < 6; ++c) {
                uint4 q = bsrc[c] ? pack2(bpre[c][0], bpre[c][1])
                                  : make_uint4(0u, 0u, 0u, 0u);
                *(uint4*)(smem + (cur ^ 1) * 24576 + bdst[c]) = q;
            }
            union { unsigned short u[8]; short8 s8; } pa;
            pa.u[0]=f2bf(apre0.x); pa.u[1]=f2bf(apre0.y); pa.u[2]=f2bf(apre0.z); pa.u[3]=f2bf(apre0.w);
            pa.u[4]=f2bf(apre1.x); pa.u[5]=f2bf(apre1.y); pa.u[6]=f2bf(apre1.z); pa.u[7]=f2bf(apre1.w);
            areg = pa.s8;
        }
        __syncthreads();
    }

    // acc -> Tsm (f32), C/D mapping col=lane&15, row=(lane>>4)*4+j
#pragma unroll
    for (int n = 0; n < 3; ++n)
#pragma unroll
        for (int j = 0; j < 4; ++j)
            Tsm[l16 * 4 + j][wid * 48 + n * 16 + l15] = acc[n][j];
    __syncthreads();

    // softmax + coef: 8 threads per token (16 tokens x 8 experts)
    if (t < 128) {
        const int tok = t >> 3, e = t & 7;
        float l[8];
#pragma unroll
        for (int i = 0; i < 8; ++i) l[i] = Tsm[tok][128 + i];
        float m = l[0];
#pragma unroll
        for (int i = 1; i < 8; ++i) m = fmaxf(m, l[i]);
        float s = 0.f;
#pragma unroll
        for (int i = 0; i < 8; ++i) s += __expf(l[i] - m);
        const float g = __expf(l[e] - m) / s * 0.0625f;   // gate * 1/R
        union { unsigned short u[16]; uint4 q[2]; } pk;
#pragma unroll
        for (int jj = 0; jj < 16; ++jj) pk.u[jj] = f2bf(g * Tsm[tok][e * 16 + jj]);
        uint4* dst = (uint4*)(Xcat + (size_t)(row0 + tok) * XLD + 1024 + e * 16);
        dst[0] = pk.q[0]; dst[1] = pk.q[1];
    }
}

// ---- GEMM2: out = Xcat @ Wcat^T (K=1152), 128x64, grid 512 — r14 verbatim --
__global__ __launch_bounds__(256) void k_gemm2(const __hip_bfloat16* __restrict__ A,
                                               const __hip_bfloat16* __restrict__ B,
                                               float* __restrict__ out) {
    __shared__ char smem[49152];                   // A: 2x16KB @0; B: 2x8KB @32768
    const int b = blockIdx.x;
    const int xcd = b & 7, j = b >> 3;
    const int bx = xcd * 4 + (j & 3), by = j >> 2;
    const int row0 = bx * 128, col0 = by * 64;

    const int t = threadIdx.x, lane = t & 63, wid = t >> 6;
    const int wr = wid >> 1, wc = wid & 1;
    const int l7 = lane & 7, l8 = lane >> 3, l15 = lane & 15, l16 = lane >> 4;
    const int scol = ((l7 ^ l8) << 3);

    f32x4 zf = {0.f, 0.f, 0.f, 0.f};
    f32x4 acc[4][2];
#pragma unroll
    for (int m = 0; m < 4; ++m)
#pragma unroll
        for (int n = 0; n < 2; ++n) acc[m][n] = zf;

    int aoff[4], boff[2], sw[2];
#pragma unroll
    for (int m = 0; m < 4; ++m) aoff[m] = (wr * 64 + m * 16 + l15) * 128;
#pragma unroll
    for (int n = 0; n < 2; ++n) boff[n] = (wc * 32 + n * 16 + l15) * 128;
#pragma unroll
    for (int ks = 0; ks < 2; ++ks) sw[ks] = (((ks * 4 + l16) ^ l7) << 4);

#define G2_STAGE(buf, kt)                                                      \
    {                                                                          \
        const int k0_ = (kt) << 6;                                             \
        _Pragma("unroll")                                                      \
        for (int i = 0; i < 4; ++i) {                                          \
            int ci = wid * 4 + i;                                              \
            gload16(A + (size_t)(row0 + ci * 8 + l8) * XLD + k0_ + scol,       \
                    smem + (buf) * 16384 + ci * 1024);                         \
        }                                                                      \
        _Pragma("unroll")                                                      \
        for (int i = 0; i < 2; ++i) {                                          \
            int cj = wid * 2 + i;                                              \
            gload16(B + (size_t)(col0 + cj * 8 + l8) * KTOT + k0_ + scol,      \
                    smem + 32768 + (buf) * 8192 + cj * 1024);                  \
        }                                                                      \
    }

#define G2_COMP(buf)                                                           \
    {                                                                          \
        const char* Ab = smem + (buf) * 16384;                                 \
        const char* Bb = smem + 32768 + (buf) * 8192;                          \
        _Pragma("unroll")                                                      \
        for (int ks = 0; ks < 2; ++ks) {                                       \
            short8 af[4], bf[2];                                               \
            _Pragma("unroll")                                                  \
            for (int m = 0; m < 4; ++m)                                        \
                af[m] = *(const short8*)(Ab + aoff[m] + sw[ks]);               \
            _Pragma("unroll")                                                  \
            for (int n = 0; n < 2; ++n)                                        \
                bf[n] = *(const short8*)(Bb + boff[n] + sw[ks]);               \
            _Pragma("unroll")                                                  \
            for (int m = 0; m < 4; ++m)                                        \
                _Pragma("unroll")                                              \
                for (int n = 0; n < 2; ++n)                                    \
                    acc[m][n] = __builtin_amdgcn_mfma_f32_16x16x32_bf16(       \
                        af[m], bf[n], acc[m][n], 0, 0, 0);                     \
        }                                                                      \
    }

    G2_STAGE(0, 0);
    int cur = 0;
    for (int kt = 0; kt < 18; ++kt) {
        if (kt < 17) {
            G2_STAGE(cur ^ 1, kt + 1);
            asm volatile("s_waitcnt vmcnt(6)" ::: "memory");
        } else {
            asm volatile("s_waitcnt vmcnt(0)" ::: "memory");
        }
        __builtin_amdgcn_s_barrier();
        G2_COMP(cur);
        __builtin_amdgcn_s_barrier();
        cur ^= 1;
    }

#pragma unroll
    for (int m = 0; m < 4; ++m)
#pragma unroll
        for (int n = 0; n < 2; ++n)
#pragma unroll
            for (int jj = 0; jj < 4; ++jj)
                out[(size_t)(row0 + wr * 64 + m * 16 + l16 * 4 + jj) * DOUT
                    + col0 + wc * 32 + n * 16 + l15] = acc[m][n][jj];
#undef G2_STAGE
#undef G2_COMP
}

extern "C" void kernel_launch(void* const* d_in, const int* in_sizes, int n_in,
                              void* d_out, int out_size, void* d_ws, size_t ws_size,
                              hipStream_t stream) {
    const float* x      = (const float*)d_in[0];   // (4,1024,1024)
    const float* weight = (const float*)d_in[1];   // (1024,1024)
    const float* gate_w = (const float*)d_in[2];   // (8,1024)
    const float* lora_U = (const float*)d_in[3];   // (8,16,1024)
    const float* lora_V = (const float*)d_in[4];   // (8,1024,16)
    float* out = (float*)d_out;

    char* ws = (char*)d_ws;
    __hip_bfloat16* Xcat = (__hip_bfloat16*)ws;                        // 4096x1152 (9.44 MB)
    __hip_bfloat16* Wcat = (__hip_bfloat16*)(ws + 9437184);            // 1024x1152 (2.36 MB)

    k_prep_g1<<<2880, 256, 0, stream>>>(x, lora_U, gate_w, weight, lora_V, Xcat, Wcat);
    k_gemm2<<<512, 256, 0, stream>>>(Xcat, Wcat, out);
}